// Round 5
// baseline (52.732 us; speedup 1.0000x reference)
//
#include <hip/hip_runtime.h>

#define B_N 8192
#define K_CL 64
#define CAP 512
#define INF_F 3.0e38f

// No sort. Each block (ci<cj) filters the 8192 points for its two clusters
// into LDS lists, then brute-forces the min pairwise distance.
// ws layout (floats): [0,4096) hinges[64*64]

__global__ __launch_bounds__(256) void pair_min_kernel(
    const int* __restrict__ labels, const float2* __restrict__ coords,
    float* __restrict__ hinges) {
    int ci = blockIdx.x, cj = blockIdx.y;
    if (ci >= cj) return;                 // uniform per block
    __shared__ float2 ipts[CAP];
    __shared__ float2 jpts[CAP];
    __shared__ int nIc, nJc;
    int tid = threadIdx.x;
    if (tid == 0) { nIc = 0; nJc = 0; }
    __syncthreads();

    // scan all labels: 8 x int4 per thread (coalesced), gather matches to LDS
#pragma unroll
    for (int k = 0; k < 8; ++k) {
        int v4 = tid + k * 256;                       // int4 index
        int4 lb = reinterpret_cast<const int4*>(labels)[v4];
        int lab[4] = {lb.x, lb.y, lb.z, lb.w};
#pragma unroll
        for (int c = 0; c < 4; ++c) {
            if (lab[c] == ci) {
                int p = atomicAdd(&nIc, 1);
                if (p < CAP) ipts[p] = coords[v4 * 4 + c];
            } else if (lab[c] == cj) {
                int p = atomicAdd(&nJc, 1);
                if (p < CAP) jpts[p] = coords[v4 * 4 + c];
            }
        }
    }
    __syncthreads();
    int nI = min(nIc, CAP), nJ = min(nJc, CAP);

    // all-pairs min: two threads per i-point, each takes half the j range
    float myMin = INF_F;
    int half = (nJ + 1) >> 1;
    int j0 = (tid & 1) ? half : 0;
    int j1 = (tid & 1) ? nJ : half;
    for (int i = tid >> 1; i < nI; i += 128) {
        float2 pi = ipts[i];
        for (int j = j0; j < j1; ++j) {
            float dx = pi.x - jpts[j].x;
            float dy = pi.y - jpts[j].y;
            myMin = fminf(myMin, dx * dx + dy * dy);
        }
    }

    // block-reduce min: wave64 shuffle then LDS across 4 waves
    for (int off = 32; off > 0; off >>= 1)
        myMin = fminf(myMin, __shfl_down(myMin, off, 64));
    __shared__ float wmin[4];
    int wave = tid >> 6, lane = tid & 63;
    if (lane == 0) wmin[wave] = myMin;
    __syncthreads();
    if (tid == 0) {
        float m = fminf(fminf(wmin[0], wmin[1]), fminf(wmin[2], wmin[3]));
        float h = 1.0f - sqrtf(m);
        hinges[ci * K_CL + cj] = h > 0.0f ? h : 0.0f;
    }
}

__global__ void reduce_hinge_kernel(const float* __restrict__ hinges,
                                    float* __restrict__ out) {
    int tid = threadIdx.x;
    float s = 0.0f;
    for (int p = tid; p < K_CL * K_CL; p += 256) {
        int ci = p >> 6, cj = p & 63;
        if (ci < cj) s += hinges[p];
    }
    for (int off = 32; off > 0; off >>= 1)
        s += __shfl_down(s, off, 64);
    __shared__ float wsum[4];
    int wave = tid >> 6, lane = tid & 63;
    if (lane == 0) wsum[wave] = s;
    __syncthreads();
    if (tid == 0)
        out[0] = (wsum[0] + wsum[1] + wsum[2] + wsum[3]) / 2016.0f;
}

extern "C" void kernel_launch(void* const* d_in, const int* in_sizes, int n_in,
                              void* d_out, int out_size, void* d_ws, size_t ws_size,
                              hipStream_t stream) {
    const int*    labels = (const int*)d_in[1];     // cluster_labels (int32)
    const float2* coords = (const float2*)d_in[2];  // manifold_coords [8192,2] f32
    float* out    = (float*)d_out;
    float* hinges = (float*)d_ws;

    dim3 grid(K_CL, K_CL);
    pair_min_kernel<<<grid, 256, 0, stream>>>(labels, coords, hinges);
    reduce_hinge_kernel<<<1, 256, 0, stream>>>(hinges, out);
}

// Round 6
// 29.696 us; speedup vs baseline: 1.7757x; 1.7757x over previous
//
#include <hip/hip_runtime.h>

#define B_N 8192
#define K_CL 64
#define CAP 256
#define INF_F 3.0e38f

// Pipeline:
//  A) gather_kernel: 64 blocks, block c compacts cluster-c points into
//     lists[c*256 ..] via ballot compaction (1 LDS atomic per wave-ballot).
//  B) pair_min_kernel: 2016 active blocks, each brute-forces min dist
//     between two compacted lists (L2-hot, ~2KB).
//  C) reduce_hinge_kernel: mean of hinges.
// ws layout (floats): [0,32768) lists (float2[64*256]) |
// [32768,32832) cnts (int[64]) | [32832,36928) hinges[64*64]

__global__ __launch_bounds__(256) void gather_kernel(
    const int* __restrict__ labels, const float2* __restrict__ coords,
    float2* __restrict__ lists, int* __restrict__ cnts) {
    int c = blockIdx.x;
    __shared__ int cnt;
    int tid = threadIdx.x;
    int lane = tid & 63;
    if (tid == 0) cnt = 0;
    __syncthreads();
#pragma unroll
    for (int k = 0; k < 8; ++k) {
        int v4 = tid + k * 256;                        // int4 index
        int4 lb = reinterpret_cast<const int4*>(labels)[v4];
        int lab[4] = {lb.x, lb.y, lb.z, lb.w};
#pragma unroll
        for (int cc = 0; cc < 4; ++cc) {
            bool m = (lab[cc] == c);
            unsigned long long mask = __ballot(m);
            if (mask) {                                 // wave-uniform
                int wb = 0;
                if (lane == 0) wb = atomicAdd(&cnt, __popcll(mask));
                wb = __shfl(wb, 0, 64);
                if (m) {
                    int pos = wb + __popcll(mask & ((1ull << lane) - 1));
                    if (pos < CAP) lists[c * CAP + pos] = coords[v4 * 4 + cc];
                }
            }
        }
    }
    __syncthreads();
    if (tid == 0) cnts[c] = min(cnt, CAP);
}

__global__ __launch_bounds__(256) void pair_min_kernel(
    const float2* __restrict__ lists, const int* __restrict__ cnts,
    float* __restrict__ hinges) {
    int ci = blockIdx.x, cj = blockIdx.y;
    if (ci >= cj) return;                 // uniform per block
    int nI = cnts[ci], nJ = cnts[cj];
    int tid = threadIdx.x;
    __shared__ float2 jpt[CAP];
    if (tid < nJ) jpt[tid] = lists[cj * CAP + tid];
    bool valid = tid < nI;
    float2 pi = make_float2(0.0f, 0.0f);
    if (valid) pi = lists[ci * CAP + tid];
    __syncthreads();

    // 4 accumulators to break the fminf dependency chain
    float m0 = INF_F, m1 = INF_F, m2 = INF_F, m3 = INF_F;
    if (valid) {
        int j = 0;
        for (; j + 3 < nJ; j += 4) {
            float2 a = jpt[j], b = jpt[j + 1], c = jpt[j + 2], d = jpt[j + 3];
            float dx0 = pi.x - a.x, dy0 = pi.y - a.y;
            float dx1 = pi.x - b.x, dy1 = pi.y - b.y;
            float dx2 = pi.x - c.x, dy2 = pi.y - c.y;
            float dx3 = pi.x - d.x, dy3 = pi.y - d.y;
            m0 = fminf(m0, dx0 * dx0 + dy0 * dy0);
            m1 = fminf(m1, dx1 * dx1 + dy1 * dy1);
            m2 = fminf(m2, dx2 * dx2 + dy2 * dy2);
            m3 = fminf(m3, dx3 * dx3 + dy3 * dy3);
        }
        for (; j < nJ; ++j) {
            float dx = pi.x - jpt[j].x, dy = pi.y - jpt[j].y;
            m0 = fminf(m0, dx * dx + dy * dy);
        }
    }
    float myMin = fminf(fminf(m0, m1), fminf(m2, m3));

    // block-reduce min: wave64 shuffle then LDS across 4 waves
    for (int off = 32; off > 0; off >>= 1)
        myMin = fminf(myMin, __shfl_down(myMin, off, 64));
    __shared__ float wmin[4];
    int wave = tid >> 6, lane = tid & 63;
    if (lane == 0) wmin[wave] = myMin;
    __syncthreads();
    if (tid == 0) {
        float m = fminf(fminf(wmin[0], wmin[1]), fminf(wmin[2], wmin[3]));
        float h = 1.0f - sqrtf(m);
        hinges[ci * K_CL + cj] = h > 0.0f ? h : 0.0f;
    }
}

__global__ void reduce_hinge_kernel(const float* __restrict__ hinges,
                                    float* __restrict__ out) {
    int tid = threadIdx.x;
    float s = 0.0f;
    for (int p = tid; p < K_CL * K_CL; p += 256) {
        int ci = p >> 6, cj = p & 63;
        if (ci < cj) s += hinges[p];
    }
    for (int off = 32; off > 0; off >>= 1)
        s += __shfl_down(s, off, 64);
    __shared__ float wsum[4];
    int wave = tid >> 6, lane = tid & 63;
    if (lane == 0) wsum[wave] = s;
    __syncthreads();
    if (tid == 0)
        out[0] = (wsum[0] + wsum[1] + wsum[2] + wsum[3]) / 2016.0f;
}

extern "C" void kernel_launch(void* const* d_in, const int* in_sizes, int n_in,
                              void* d_out, int out_size, void* d_ws, size_t ws_size,
                              hipStream_t stream) {
    const int*    labels = (const int*)d_in[1];     // cluster_labels (int32)
    const float2* coords = (const float2*)d_in[2];  // manifold_coords [8192,2] f32
    float* out = (float*)d_out;

    float2* lists  = (float2*)d_ws;
    int*    cnts   = (int*)((float*)d_ws + 2 * K_CL * CAP);
    float*  hinges = (float*)d_ws + 2 * K_CL * CAP + 64;

    gather_kernel<<<K_CL, 256, 0, stream>>>(labels, coords, lists, cnts);
    dim3 grid(K_CL, K_CL);
    pair_min_kernel<<<grid, 256, 0, stream>>>(lists, cnts, hinges);
    reduce_hinge_kernel<<<1, 256, 0, stream>>>(hinges, out);
}